// Round 1
// baseline (349.164 us; speedup 1.0000x reference)
//
#include <hip/hip_runtime.h>
#include <stdint.h>

#define NB 4096
#define TT 64
#define CC 128
#define HH 64
#define BPB 4          // batches per block; grid = 1024 = 4 blocks/CU x 256 CU exactly resident
#define QSTR 72        // q/k/vT LDS row stride: 64 + 8 pad (144 B rows; (l15+quad)%8 bank spread)

typedef __bf16 bf16x8 __attribute__((ext_vector_type(8)));
typedef float f32x4 __attribute__((ext_vector_type(4)));
typedef unsigned short us4 __attribute__((ext_vector_type(4)));

__device__ __forceinline__ unsigned short f2bf(float f) {
  union { float f; uint32_t u; } a; a.f = f;
  uint32_t u = a.u;
  u += 0x7fffu + ((u >> 16) & 1u);   // round-to-nearest-even
  return (unsigned short)(u >> 16);
}

// hardware RNE f32->bf16 (v_cvt_pk_bf16_f32); same rounding as f2bf, 1 op instead of 4
__device__ __forceinline__ unsigned short bfbits(float f) {
  union { __bf16 b; unsigned short u; } c; c.b = (__bf16)f; return c.u;
}

// Pre-swizzle the three [C,H] fp32 weight matrices into MFMA B-fragment order:
// wz[((mat*4 + nt)*4 + ks)*64 + lane][8] = W^T[h = nt*16 + (lane&15)][c = ks*32 + (lane>>4)*8 + j]
__global__ void swizzle_w_kernel(const float* __restrict__ Wq,
                                 const float* __restrict__ Wk,
                                 const float* __restrict__ Wv,
                                 unsigned short* __restrict__ wz) {
  int i = blockIdx.x * 256 + threadIdx.x;   // [0, 3*16*64)
  if (i >= 3 * 16 * 64) return;
  int mat  = i >> 10;
  int rem  = i & 1023;
  int frag = rem >> 6;         // nt*4 + ks
  int lane = rem & 63;
  int nt = frag >> 2, ks = frag & 3;
  int quad = lane >> 4, l15 = lane & 15;
  int h  = nt * 16 + l15;
  int c0 = ks * 32 + quad * 8;
  const float* W = (mat == 0) ? Wq : (mat == 1) ? Wk : Wv;
  unsigned short* o = wz + (size_t)i * 8;
  #pragma unroll
  for (int j = 0; j < 8; ++j) o[j] = f2bf(W[(c0 + j) * HH + h]);
}

// Weights are read DIRECTLY from global wz each batch (48 KiB table, shared by all
// blocks -> L2-resident). Dropping the 48 KiB LDS copy takes LDS 75->27.6 KiB, so
// occupancy goes 2 -> 4 blocks/CU (the kernel is latency-bound: MfmaUtil 8%,
// VALUBusy 19%, Occupancy 17%).
__global__ __launch_bounds__(256, 4)
void attn_kernel(const float* __restrict__ x,
                 const unsigned short* __restrict__ wz,
                 float* __restrict__ out) {
  __shared__ unsigned short qs[64 * QSTR];        // q rows (wave-private); reused for P
  __shared__ unsigned short ks_[64 * QSTR];       // k row-major [t][h]
  __shared__ unsigned short vts[64 * QSTR];       // v transposed [h][t]

  const int tid  = threadIdx.x;
  const int wave = tid >> 6;
  const int lane = tid & 63;
  const int quad = lane >> 4;
  const int l15  = lane & 15;
  const int mbase = wave * 16;
  const float scale = 0.08838834764831845f;  // 128^-0.5 (embed dim, per reference)
  const int b0 = blockIdx.x * BPB;

  // ---- prefetch x for batch 0
  f32x4 raw[8];
  {
    const float* xr = x + ((size_t)b0 * TT + mbase + l15) * CC + quad * 8;
    #pragma unroll
    for (int ksi = 0; ksi < 4; ++ksi) {
      raw[2 * ksi]     = *(const f32x4*)(xr + ksi * 32);
      raw[2 * ksi + 1] = *(const f32x4*)(xr + ksi * 32 + 4);
    }
  }

  const unsigned short* wl = wz + (size_t)lane * 8;   // per-lane base into fragment table

  for (int bi = 0; bi < BPB; ++bi) {
    const int b = b0 + bi;

    // ---- convert prefetched x to bf16 A-fragments: A[m=l15][k=quad*8+j]
    bf16x8 xfrag[4];
    #pragma unroll
    for (int ksi = 0; ksi < 4; ++ksi) {
      bf16x8 f;
      #pragma unroll
      for (int j = 0; j < 4; ++j) {
        f[j]     = (__bf16)raw[2 * ksi][j];
        f[j + 4] = (__bf16)raw[2 * ksi + 1][j];
      }
      xfrag[ksi] = f;
    }

    // ---- issue next batch's x loads (in flight across this batch's compute)
    if (bi < BPB - 1) {
      const float* xr = x + ((size_t)(b + 1) * TT + mbase + l15) * CC + quad * 8;
      #pragma unroll
      for (int ksi = 0; ksi < 4; ++ksi) {
        raw[2 * ksi]     = *(const f32x4*)(xr + ksi * 32);
        raw[2 * ksi + 1] = *(const f32x4*)(xr + ksi * 32 + 4);
      }
    }

    if (bi > 0) __syncthreads();   // all waves done reading ks_/vts of previous batch

    // ---- Phase 1: q, k, v projections; B-fragments straight from global (L2-hit)
    #pragma unroll
    for (int mat = 0; mat < 3; ++mat) {
      #pragma unroll
      for (int nt = 0; nt < 4; ++nt) {
        f32x4 acc = {0.f, 0.f, 0.f, 0.f};
        #pragma unroll
        for (int ksi = 0; ksi < 4; ++ksi) {
          bf16x8 bfrag = *(const bf16x8*)(wl + (size_t)(((mat * 4 + nt) * 4 + ksi) * 64) * 8);
          acc = __builtin_amdgcn_mfma_f32_16x16x32_bf16(xfrag[ksi], bfrag, acc, 0, 0, 0);
        }
        // C/D: col = nt*16 + l15, row = mbase + quad*4 + r
        if (mat == 2) {
          // v stored transposed: rows r are CONSECUTIVE in vts -> one 8B packed write
          us4 pk;
          #pragma unroll
          for (int r = 0; r < 4; ++r) pk[r] = bfbits(acc[r]);
          *(us4*)&vts[(nt * 16 + l15) * QSTR + mbase + quad * 4] = pk;
        } else {
          #pragma unroll
          for (int r = 0; r < 4; ++r) {
            int row = mbase + quad * 4 + r;
            int col = nt * 16 + l15;
            unsigned short v = bfbits(acc[r]);
            if (mat == 0) qs[row * QSTR + col] = v;
            else          ks_[row * QSTR + col] = v;
          }
        }
      }
    }
    __syncthreads();   // k, vT (cross-wave) ready

    // ---- Phase 2: S = q k^T * scale, causal mask, softmax -> P into qs (wave-private)
    f32x4 sc[4];
    {
      bf16x8 aq[2];
      #pragma unroll
      for (int k2 = 0; k2 < 2; ++k2)
        aq[k2] = *(const bf16x8*)&qs[(mbase + l15) * QSTR + k2 * 32 + quad * 8];
      #pragma unroll
      for (int nt = 0; nt < 4; ++nt) {
        f32x4 acc = {0.f, 0.f, 0.f, 0.f};
        #pragma unroll
        for (int k2 = 0; k2 < 2; ++k2) {
          bf16x8 bk = *(const bf16x8*)&ks_[(nt * 16 + l15) * QSTR + k2 * 32 + quad * 8];
          acc = __builtin_amdgcn_mfma_f32_16x16x32_bf16(aq[k2], bk, acc, 0, 0, 0);
        }
        sc[nt] = acc;
      }
    }
    #pragma unroll
    for (int r = 0; r < 4; ++r) {
      int row = mbase + quad * 4 + r;
      float vals[4];
      #pragma unroll
      for (int nt = 0; nt < 4; ++nt) {
        int col = nt * 16 + l15;
        float v = sc[nt][r] * scale;
        vals[nt] = (col <= row) ? v : -__builtin_inff();
      }
      float m = fmaxf(fmaxf(vals[0], vals[1]), fmaxf(vals[2], vals[3]));
      #pragma unroll
      for (int d = 1; d < 16; d <<= 1) m = fmaxf(m, __shfl_xor(m, d, 64));
      float s = 0.f;
      #pragma unroll
      for (int nt = 0; nt < 4; ++nt) { vals[nt] = __expf(vals[nt] - m); s += vals[nt]; }
      #pragma unroll
      for (int d = 1; d < 16; d <<= 1) s += __shfl_xor(s, d, 64);
      float inv = 1.f / s;
      // P overwrites this wave's own q rows; rows are wave-private -> no barrier
      #pragma unroll
      for (int nt = 0; nt < 4; ++nt)
        qs[row * QSTR + nt * 16 + l15] = bfbits(vals[nt] * inv);
    }

    // ---- Phase 3: O = P @ V
    bf16x8 ap[2];
    #pragma unroll
    for (int k2 = 0; k2 < 2; ++k2)
      ap[k2] = *(const bf16x8*)&qs[(mbase + l15) * QSTR + k2 * 32 + quad * 8];
    float* ob = out + ((size_t)b * TT) * HH;
    #pragma unroll
    for (int nt = 0; nt < 4; ++nt) {
      f32x4 acc = {0.f, 0.f, 0.f, 0.f};
      #pragma unroll
      for (int k2 = 0; k2 < 2; ++k2) {
        bf16x8 bv = *(const bf16x8*)&vts[(nt * 16 + l15) * QSTR + k2 * 32 + quad * 8];
        acc = __builtin_amdgcn_mfma_f32_16x16x32_bf16(ap[k2], bv, acc, 0, 0, 0);
      }
      #pragma unroll
      for (int r = 0; r < 4; ++r) {
        int row = mbase + quad * 4 + r;
        ob[row * HH + nt * 16 + l15] = acc[r];   // fp32 store
      }
    }
  }
}

extern "C" void kernel_launch(void* const* d_in, const int* in_sizes, int n_in,
                              void* d_out, int out_size, void* d_ws, size_t ws_size,
                              hipStream_t stream) {
  const float* x  = (const float*)d_in[0];
  const float* Wq = (const float*)d_in[1];
  const float* Wk = (const float*)d_in[2];
  const float* Wv = (const float*)d_in[3];
  unsigned short* wz = (unsigned short*)d_ws;   // 3*16*64*8 bf16 = 48 KiB scratch
  float* outp = (float*)d_out;

  swizzle_w_kernel<<<(3 * 16 * 64 + 255) / 256, 256, 0, stream>>>(Wq, Wk, Wv, wz);
  attn_kernel<<<NB / BPB, 256, 0, stream>>>(x, wz, outp);
}

// Round 2
// 290.122 us; speedup vs baseline: 1.2035x; 1.2035x over previous
//
#include <hip/hip_runtime.h>
#include <stdint.h>

#define NB 4096
#define TT 64
#define CC 128
#define HH 64
#define BPB 4          // batches per block; grid = 1024 = 4 blocks/CU x 256 CU exactly resident

typedef __bf16 bf16x8 __attribute__((ext_vector_type(8)));
typedef float f32x4 __attribute__((ext_vector_type(4)));
typedef unsigned short us4 __attribute__((ext_vector_type(4)));

__device__ __forceinline__ unsigned short f2bf(float f) {
  union { float f; uint32_t u; } a; a.f = f;
  uint32_t u = a.u;
  u += 0x7fffu + ((u >> 16) & 1u);   // round-to-nearest-even
  return (unsigned short)(u >> 16);
}

// hardware RNE f32->bf16 (v_cvt_pk_bf16_f32); same rounding as f2bf, 1 op instead of 4
__device__ __forceinline__ unsigned short bfbits(float f) {
  union { __bf16 b; unsigned short u; } c; c.b = (__bf16)f; return c.u;
}

// Pre-swizzle the three [C,H] fp32 weight matrices into MFMA B-fragment order:
// wz[((mat*4 + nt)*4 + ks)*64 + lane][8] = W^T[h = nt*16 + (lane&15)][c = ks*32 + (lane>>4)*8 + j]
__global__ void swizzle_w_kernel(const float* __restrict__ Wq,
                                 const float* __restrict__ Wk,
                                 const float* __restrict__ Wv,
                                 unsigned short* __restrict__ wz) {
  int i = blockIdx.x * 256 + threadIdx.x;   // [0, 3*16*64)
  if (i >= 3 * 16 * 64) return;
  int mat  = i >> 10;
  int rem  = i & 1023;
  int frag = rem >> 6;         // nt*4 + ks
  int lane = rem & 63;
  int nt = frag >> 2, ks = frag & 3;
  int quad = lane >> 4, l15 = lane & 15;
  int h  = nt * 16 + l15;
  int c0 = ks * 32 + quad * 8;
  const float* W = (mat == 0) ? Wq : (mat == 1) ? Wk : Wv;
  unsigned short* o = wz + (size_t)i * 8;
  #pragma unroll
  for (int j = 0; j < 8; ++j) o[j] = f2bf(W[(c0 + j) * HH + h]);
}

// Wave-specialized weights: wave w permanently holds B-fragments for (mat,nt) pairs
// pi = 3w..3w+2 in 48 VGPRs (loaded ONCE -> no per-batch churn, no spill; round-1's
// per-batch global weight loads spilled: WRITE_SIZE 224 MB vs 67 MB output).
// Phase 1 is column-decomposed: each wave computes its 3 projection column-tiles for
// ALL 64 rows, reading x A-fragments from a cooperatively staged LDS tile.
// All LDS buffers use a 16B-chunk XOR swizzle (chunk ^= row&7) instead of +8 pad:
// same 2-way bank spread on ds_read_b128, but LDS = 16384 + 3*8192 = 40960 B exactly
// -> 4 blocks/CU (was 2).
__global__ __launch_bounds__(256, 4)
void attn_kernel(const float* __restrict__ x,
                 const unsigned short* __restrict__ wz,
                 float* __restrict__ out) {
  __shared__ unsigned short xs [64 * 128];  // x tile bf16 [t][c], swizzled
  __shared__ unsigned short qs [64 * 64];   // q rows [t][h]; reused for P
  __shared__ unsigned short ks_[64 * 64];   // k rows [t][h]
  __shared__ unsigned short vts[64 * 64];   // v transposed [h][t]

  const int tid  = threadIdx.x;
  const int wave = tid >> 6;
  const int lane = tid & 63;
  const int quad = lane >> 4;
  const int l15  = lane & 15;
  const int l7   = l15 & 7;
  const int mbase = wave * 16;
  const float scale = 0.08838834764831845f;  // 128^-0.5 (embed dim, per reference)

  // ---- one-time: this wave's 12 weight B-fragments -> registers (48 VGPRs)
  bf16x8 wreg[3][4];
  #pragma unroll
  for (int p = 0; p < 3; ++p) {
    const int pi = wave * 3 + p;
    #pragma unroll
    for (int ks = 0; ks < 4; ++ks)
      wreg[p][ks] = *(const bf16x8*)(wz + (size_t)(((pi << 2) + ks) * 64 + lane) * 8);
  }

  const int b0 = blockIdx.x * BPB;

  for (int bi = 0; bi < BPB; ++bi) {
    const int b = b0 + bi;
    if (bi > 0) __syncthreads();   // all waves done reading previous batch's LDS

    // ---- stage x tile to LDS as bf16 (4 x 16B chunks per thread, coalesced reads)
    #pragma unroll
    for (int k = 0; k < 4; ++k) {
      const int i = tid + 256 * k;          // chunk id: row*16 + c
      const int row = i >> 4, c = i & 15;
      const float* src = x + ((size_t)b * TT + row) * CC + c * 8;
      const f32x4 lo = *(const f32x4*)src;
      const f32x4 hi = *(const f32x4*)(src + 4);
      bf16x8 v;
      #pragma unroll
      for (int j = 0; j < 4; ++j) { v[j] = (__bf16)lo[j]; v[j + 4] = (__bf16)hi[j]; }
      *(bf16x8*)&xs[row * 128 + ((c ^ (row & 7)) << 3)] = v;
    }
    __syncthreads();   // xs ready

    // ---- Phase 1: for each row-tile, this wave's 3 (mat,nt) projection tiles
    #pragma unroll
    for (int mt = 0; mt < 4; ++mt) {
      bf16x8 xf[4];    // A-fragments: row = mt*16+l15, k = ks*32+quad*8+j
      #pragma unroll
      for (int ks = 0; ks < 4; ++ks)
        xf[ks] = *(const bf16x8*)&xs[(mt * 16 + l15) * 128 + ((((ks << 2) + quad) ^ l7) << 3)];
      #pragma unroll
      for (int p = 0; p < 3; ++p) {
        f32x4 acc = {0.f, 0.f, 0.f, 0.f};
        #pragma unroll
        for (int ks = 0; ks < 4; ++ks)
          acc = __builtin_amdgcn_mfma_f32_16x16x32_bf16(xf[ks], wreg[p][ks], acc, 0, 0, 0);
        // C/D: col = nt*16 + l15, row = mt*16 + quad*4 + r
        const int pi = wave * 3 + p;
        const int mat = pi >> 2, nt = pi & 3;
        if (mat == 2) {
          // v stored transposed: 4 consecutive t -> one 8B packed write (stays in chunk)
          const int h  = (nt << 4) + l15;
          const int t0 = (mt << 4) + (quad << 2);
          us4 pk;
          #pragma unroll
          for (int r = 0; r < 4; ++r) pk[r] = bfbits(acc[r]);
          *(us4*)&vts[(h << 6) + (((t0 >> 3) ^ (h & 7)) << 3) + (t0 & 7)] = pk;
        } else {
          unsigned short* dst = (mat == 0) ? qs : ks_;
          const int col = (nt << 4) + l15;
          const int ch = col >> 3, cj = col & 7;
          #pragma unroll
          for (int r = 0; r < 4; ++r) {
            const int row = (mt << 4) + (quad << 2) + r;
            dst[(row << 6) + ((ch ^ (row & 7)) << 3) + cj] = bfbits(acc[r]);
          }
        }
      }
    }
    __syncthreads();   // q, k, vT ready (cross-wave)

    // ---- Phase 2: S = q k^T * scale, causal mask, softmax -> P into qs (wave-private rows)
    f32x4 sc[4];
    {
      bf16x8 aq[2];
      #pragma unroll
      for (int k2 = 0; k2 < 2; ++k2)
        aq[k2] = *(const bf16x8*)&qs[((mbase + l15) << 6) + ((((k2 << 2) + quad) ^ l7) << 3)];
      #pragma unroll
      for (int nt = 0; nt < 4; ++nt) {
        f32x4 acc = {0.f, 0.f, 0.f, 0.f};
        #pragma unroll
        for (int k2 = 0; k2 < 2; ++k2) {
          const bf16x8 bk = *(const bf16x8*)&ks_[(((nt << 4) + l15) << 6) + ((((k2 << 2) + quad) ^ l7) << 3)];
          acc = __builtin_amdgcn_mfma_f32_16x16x32_bf16(aq[k2], bk, acc, 0, 0, 0);
        }
        sc[nt] = acc;
      }
    }
    #pragma unroll
    for (int r = 0; r < 4; ++r) {
      const int row = mbase + (quad << 2) + r;
      float vals[4];
      #pragma unroll
      for (int nt = 0; nt < 4; ++nt) {
        const int col = (nt << 4) + l15;
        const float v = sc[nt][r] * scale;
        vals[nt] = (col <= row) ? v : -__builtin_inff();
      }
      float m = fmaxf(fmaxf(vals[0], vals[1]), fmaxf(vals[2], vals[3]));
      #pragma unroll
      for (int d = 1; d < 16; d <<= 1) m = fmaxf(m, __shfl_xor(m, d, 64));
      float s = 0.f;
      #pragma unroll
      for (int nt = 0; nt < 4; ++nt) { vals[nt] = __expf(vals[nt] - m); s += vals[nt]; }
      #pragma unroll
      for (int d = 1; d < 16; d <<= 1) s += __shfl_xor(s, d, 64);
      const float inv = 1.f / s;
      const int rs = row & 7;
      // P overwrites this wave's own q rows; rows are wave-private -> no barrier
      #pragma unroll
      for (int nt = 0; nt < 4; ++nt) {
        const int col = (nt << 4) + l15;
        qs[(row << 6) + (((col >> 3) ^ rs) << 3) + (col & 7)] = bfbits(vals[nt] * inv);
      }
    }

    // ---- Phase 3: O = P @ V
    bf16x8 ap[2];
    #pragma unroll
    for (int k2 = 0; k2 < 2; ++k2)
      ap[k2] = *(const bf16x8*)&qs[((mbase + l15) << 6) + ((((k2 << 2) + quad) ^ l7) << 3)];
    float* ob = out + ((size_t)b * TT) * HH;
    #pragma unroll
    for (int nt = 0; nt < 4; ++nt) {
      f32x4 acc = {0.f, 0.f, 0.f, 0.f};
      #pragma unroll
      for (int k2 = 0; k2 < 2; ++k2) {
        const bf16x8 bv = *(const bf16x8*)&vts[(((nt << 4) + l15) << 6) + ((((k2 << 2) + quad) ^ l7) << 3)];
        acc = __builtin_amdgcn_mfma_f32_16x16x32_bf16(ap[k2], bv, acc, 0, 0, 0);
      }
      #pragma unroll
      for (int r = 0; r < 4; ++r)
        ob[(mbase + (quad << 2) + r) * HH + (nt << 4) + l15] = acc[r];   // fp32 store
    }
  }
}

extern "C" void kernel_launch(void* const* d_in, const int* in_sizes, int n_in,
                              void* d_out, int out_size, void* d_ws, size_t ws_size,
                              hipStream_t stream) {
  const float* x  = (const float*)d_in[0];
  const float* Wq = (const float*)d_in[1];
  const float* Wk = (const float*)d_in[2];
  const float* Wv = (const float*)d_in[3];
  unsigned short* wz = (unsigned short*)d_ws;   // 3*16*64*8 bf16 = 48 KiB scratch
  float* outp = (float*)d_out;

  swizzle_w_kernel<<<(3 * 16 * 64 + 255) / 256, 256, 0, stream>>>(Wq, Wk, Wv, wz);
  attn_kernel<<<NB / BPB, 256, 0, stream>>>(x, wz, outp);
}

// Round 3
// 290.011 us; speedup vs baseline: 1.2040x; 1.0004x over previous
//
#include <hip/hip_runtime.h>
#include <stdint.h>

#define NB 4096
#define TT 64
#define CC 128
#define HH 64
#define BPB 4          // batches per block; grid = 1024 = 4 blocks/CU x 256 CU exactly resident

typedef __bf16 bf16x8 __attribute__((ext_vector_type(8)));
typedef float f32x4 __attribute__((ext_vector_type(4)));
typedef unsigned short us4 __attribute__((ext_vector_type(4)));

__device__ __forceinline__ unsigned short f2bf(float f) {
  union { float f; uint32_t u; } a; a.f = f;
  uint32_t u = a.u;
  u += 0x7fffu + ((u >> 16) & 1u);   // round-to-nearest-even
  return (unsigned short)(u >> 16);
}

// hardware RNE f32->bf16 (v_cvt_pk_bf16_f32); same rounding as f2bf, 1 op instead of 4
__device__ __forceinline__ unsigned short bfbits(float f) {
  union { __bf16 b; unsigned short u; } c; c.b = (__bf16)f; return c.u;
}

// Pre-swizzle the three [C,H] fp32 weight matrices into MFMA B-fragment order:
// wz[((mat*4 + nt)*4 + ks)*64 + lane][8] = W^T[h = nt*16 + (lane&15)][c = ks*32 + (lane>>4)*8 + j]
__global__ void swizzle_w_kernel(const float* __restrict__ Wq,
                                 const float* __restrict__ Wk,
                                 const float* __restrict__ Wv,
                                 unsigned short* __restrict__ wz) {
  int i = blockIdx.x * 256 + threadIdx.x;   // [0, 3*16*64)
  if (i >= 3 * 16 * 64) return;
  int mat  = i >> 10;
  int rem  = i & 1023;
  int frag = rem >> 6;         // nt*4 + ks
  int lane = rem & 63;
  int nt = frag >> 2, ks = frag & 3;
  int quad = lane >> 4, l15 = lane & 15;
  int h  = nt * 16 + l15;
  int c0 = ks * 32 + quad * 8;
  const float* W = (mat == 0) ? Wq : (mat == 1) ? Wk : Wv;
  unsigned short* o = wz + (size_t)i * 8;
  #pragma unroll
  for (int j = 0; j < 8; ++j) o[j] = f2bf(W[(c0 + j) * HH + h]);
}

// Wave-specialized weights: wave w permanently holds B-fragments for (mat,nt) pairs
// pi = 3w..3w+2 in 48 VGPRs, loaded ONCE before the batch loop.
// amdgpu_waves_per_eu(4,4): LDS (40960 B) already caps the CU at 4 blocks = 4 waves/EU,
// but with launch_bounds alone LLVM's allocator treats that as a MINIMUM and chased the
// 64-VGPR / 8-waves tier, spilling wreg to scratch (rounds 1-2: WRITE_SIZE 224/123 MB
// vs 67 MB output, VGPR_Count=64). Pinning max=4 allows 128 VGPRs -> no spill.
__global__ __launch_bounds__(256)
__attribute__((amdgpu_waves_per_eu(4, 4)))
void attn_kernel(const float* __restrict__ x,
                 const unsigned short* __restrict__ wz,
                 float* __restrict__ out) {
  __shared__ unsigned short xs [64 * 128];  // x tile bf16 [t][c], swizzled
  __shared__ unsigned short qs [64 * 64];   // q rows [t][h]; reused for P
  __shared__ unsigned short ks_[64 * 64];   // k rows [t][h]
  __shared__ unsigned short vts[64 * 64];   // v transposed [h][t]

  const int tid  = threadIdx.x;
  const int wave = tid >> 6;
  const int lane = tid & 63;
  const int quad = lane >> 4;
  const int l15  = lane & 15;
  const int l7   = l15 & 7;
  const int mbase = wave * 16;
  const float scale = 0.08838834764831845f;  // 128^-0.5 (embed dim, per reference)

  // ---- one-time: this wave's 12 weight B-fragments -> registers (48 VGPRs)
  bf16x8 wreg[3][4];
  #pragma unroll
  for (int p = 0; p < 3; ++p) {
    const int pi = wave * 3 + p;
    #pragma unroll
    for (int ks = 0; ks < 4; ++ks)
      wreg[p][ks] = *(const bf16x8*)(wz + (size_t)(((pi << 2) + ks) * 64 + lane) * 8);
  }

  const int b0 = blockIdx.x * BPB;

  for (int bi = 0; bi < BPB; ++bi) {
    const int b = b0 + bi;
    if (bi > 0) __syncthreads();   // all waves done reading previous batch's LDS

    // ---- stage x tile to LDS as bf16 (4 x 16B chunks per thread, coalesced reads)
    #pragma unroll
    for (int k = 0; k < 4; ++k) {
      const int i = tid + 256 * k;          // chunk id: row*16 + c
      const int row = i >> 4, c = i & 15;
      const float* src = x + ((size_t)b * TT + row) * CC + c * 8;
      const f32x4 lo = *(const f32x4*)src;
      const f32x4 hi = *(const f32x4*)(src + 4);
      bf16x8 v;
      #pragma unroll
      for (int j = 0; j < 4; ++j) { v[j] = (__bf16)lo[j]; v[j + 4] = (__bf16)hi[j]; }
      *(bf16x8*)&xs[row * 128 + ((c ^ (row & 7)) << 3)] = v;
    }
    __syncthreads();   // xs ready

    // ---- Phase 1: for each row-tile, this wave's 3 (mat,nt) projection tiles
    #pragma unroll
    for (int mt = 0; mt < 4; ++mt) {
      bf16x8 xf[4];    // A-fragments: row = mt*16+l15, k = ks*32+quad*8+j
      #pragma unroll
      for (int ks = 0; ks < 4; ++ks)
        xf[ks] = *(const bf16x8*)&xs[(mt * 16 + l15) * 128 + ((((ks << 2) + quad) ^ l7) << 3)];
      #pragma unroll
      for (int p = 0; p < 3; ++p) {
        f32x4 acc = {0.f, 0.f, 0.f, 0.f};
        #pragma unroll
        for (int ks = 0; ks < 4; ++ks)
          acc = __builtin_amdgcn_mfma_f32_16x16x32_bf16(xf[ks], wreg[p][ks], acc, 0, 0, 0);
        // C/D: col = nt*16 + l15, row = mt*16 + quad*4 + r
        const int pi = wave * 3 + p;
        const int mat = pi >> 2, nt = pi & 3;
        if (mat == 2) {
          // v stored transposed: 4 consecutive t -> one 8B packed write (stays in chunk)
          const int h  = (nt << 4) + l15;
          const int t0 = (mt << 4) + (quad << 2);
          us4 pk;
          #pragma unroll
          for (int r = 0; r < 4; ++r) pk[r] = bfbits(acc[r]);
          *(us4*)&vts[(h << 6) + (((t0 >> 3) ^ (h & 7)) << 3) + (t0 & 7)] = pk;
        } else {
          unsigned short* dst = (mat == 0) ? qs : ks_;
          const int col = (nt << 4) + l15;
          const int ch = col >> 3, cj = col & 7;
          #pragma unroll
          for (int r = 0; r < 4; ++r) {
            const int row = (mt << 4) + (quad << 2) + r;
            dst[(row << 6) + ((ch ^ (row & 7)) << 3) + cj] = bfbits(acc[r]);
          }
        }
      }
    }
    __syncthreads();   // q, k, vT ready (cross-wave)

    // ---- Phase 2: S = q k^T * scale, causal mask, softmax -> P into qs (wave-private rows)
    f32x4 sc[4];
    {
      bf16x8 aq[2];
      #pragma unroll
      for (int k2 = 0; k2 < 2; ++k2)
        aq[k2] = *(const bf16x8*)&qs[((mbase + l15) << 6) + ((((k2 << 2) + quad) ^ l7) << 3)];
      #pragma unroll
      for (int nt = 0; nt < 4; ++nt) {
        f32x4 acc = {0.f, 0.f, 0.f, 0.f};
        #pragma unroll
        for (int k2 = 0; k2 < 2; ++k2) {
          const bf16x8 bk = *(const bf16x8*)&ks_[(((nt << 4) + l15) << 6) + ((((k2 << 2) + quad) ^ l7) << 3)];
          acc = __builtin_amdgcn_mfma_f32_16x16x32_bf16(aq[k2], bk, acc, 0, 0, 0);
        }
        sc[nt] = acc;
      }
    }
    #pragma unroll
    for (int r = 0; r < 4; ++r) {
      const int row = mbase + (quad << 2) + r;
      float vals[4];
      #pragma unroll
      for (int nt = 0; nt < 4; ++nt) {
        const int col = (nt << 4) + l15;
        const float v = sc[nt][r] * scale;
        vals[nt] = (col <= row) ? v : -__builtin_inff();
      }
      float m = fmaxf(fmaxf(vals[0], vals[1]), fmaxf(vals[2], vals[3]));
      #pragma unroll
      for (int d = 1; d < 16; d <<= 1) m = fmaxf(m, __shfl_xor(m, d, 64));
      float s = 0.f;
      #pragma unroll
      for (int nt = 0; nt < 4; ++nt) { vals[nt] = __expf(vals[nt] - m); s += vals[nt]; }
      #pragma unroll
      for (int d = 1; d < 16; d <<= 1) s += __shfl_xor(s, d, 64);
      const float inv = 1.f / s;
      const int rs = row & 7;
      // P overwrites this wave's own q rows; rows are wave-private -> no barrier
      #pragma unroll
      for (int nt = 0; nt < 4; ++nt) {
        const int col = (nt << 4) + l15;
        qs[(row << 6) + (((col >> 3) ^ rs) << 3) + (col & 7)] = bfbits(vals[nt] * inv);
      }
    }

    // ---- Phase 3: O = P @ V
    bf16x8 ap[2];
    #pragma unroll
    for (int k2 = 0; k2 < 2; ++k2)
      ap[k2] = *(const bf16x8*)&qs[((mbase + l15) << 6) + ((((k2 << 2) + quad) ^ l7) << 3)];
    float* ob = out + ((size_t)b * TT) * HH;
    #pragma unroll
    for (int nt = 0; nt < 4; ++nt) {
      f32x4 acc = {0.f, 0.f, 0.f, 0.f};
      #pragma unroll
      for (int k2 = 0; k2 < 2; ++k2) {
        const bf16x8 bv = *(const bf16x8*)&vts[(((nt << 4) + l15) << 6) + ((((k2 << 2) + quad) ^ l7) << 3)];
        acc = __builtin_amdgcn_mfma_f32_16x16x32_bf16(ap[k2], bv, acc, 0, 0, 0);
      }
      #pragma unroll
      for (int r = 0; r < 4; ++r)
        ob[(mbase + (quad << 2) + r) * HH + (nt << 4) + l15] = acc[r];   // fp32 store
    }
  }
}

extern "C" void kernel_launch(void* const* d_in, const int* in_sizes, int n_in,
                              void* d_out, int out_size, void* d_ws, size_t ws_size,
                              hipStream_t stream) {
  const float* x  = (const float*)d_in[0];
  const float* Wq = (const float*)d_in[1];
  const float* Wk = (const float*)d_in[2];
  const float* Wv = (const float*)d_in[3];
  unsigned short* wz = (unsigned short*)d_ws;   // 3*16*64*8 bf16 = 48 KiB scratch
  float* outp = (float*)d_out;

  swizzle_w_kernel<<<(3 * 16 * 64 + 255) / 256, 256, 0, stream>>>(Wq, Wk, Wv, wz);
  attn_kernel<<<NB / BPB, 256, 0, stream>>>(x, wz, outp);
}

// Round 4
// 223.350 us; speedup vs baseline: 1.5633x; 1.2985x over previous
//
#include <hip/hip_runtime.h>
#include <stdint.h>

#define NB 4096
#define TT 64
#define CC 128
#define HH 64
#define BPB 4          // batches per block; grid = 1024 = 4 blocks/CU x 256 CU exactly resident

typedef __bf16 bf16x8 __attribute__((ext_vector_type(8)));
typedef float f32x4 __attribute__((ext_vector_type(4)));
typedef unsigned short us4 __attribute__((ext_vector_type(4)));

__device__ __forceinline__ unsigned short f2bf(float f) {
  union { float f; uint32_t u; } a; a.f = f;
  uint32_t u = a.u;
  u += 0x7fffu + ((u >> 16) & 1u);   // round-to-nearest-even
  return (unsigned short)(u >> 16);
}

// hardware RNE f32->bf16; same rounding as f2bf
__device__ __forceinline__ unsigned short bfbits(float f) {
  union { __bf16 b; unsigned short u; } c; c.b = (__bf16)f; return c.u;
}

// Pre-swizzle the three [C,H] fp32 weight matrices into MFMA B-fragment order:
// wz[((mat*4 + nt)*4 + ks)*64 + lane][8] = W^T[h = nt*16 + (lane&15)][c = ks*32 + (lane>>4)*8 + j]
__global__ void swizzle_w_kernel(const float* __restrict__ Wq,
                                 const float* __restrict__ Wk,
                                 const float* __restrict__ Wv,
                                 unsigned short* __restrict__ wz) {
  int i = blockIdx.x * 256 + threadIdx.x;   // [0, 3*16*64)
  if (i >= 3 * 16 * 64) return;
  int mat  = i >> 10;
  int rem  = i & 1023;
  int frag = rem >> 6;         // nt*4 + ks
  int lane = rem & 63;
  int nt = frag >> 2, ks = frag & 3;
  int quad = lane >> 4, l15 = lane & 15;
  int h  = nt * 16 + l15;
  int c0 = ks * 32 + quad * 8;
  const float* W = (mat == 0) ? Wq : (mat == 1) ? Wk : Wv;
  unsigned short* o = wz + (size_t)i * 8;
  #pragma unroll
  for (int j = 0; j < 8; ++j) o[j] = f2bf(W[(c0 + j) * HH + h]);
}

#define MFMA16(A, B, C) __builtin_amdgcn_mfma_f32_16x16x32_bf16((A), (B), (C), 0, 0, 0)

// Wave-specialized weights: wave w holds B-fragments for (mat,nt) pairs pi=3w..3w+2.
// ROUNDS 1-3 LESSON: wreg as a [3][4] array of ext-vectors was demoted to SCRATCH
// (SROA fails on non-constant GEPs before unrolling; rule #20) -> one-time 50 MB
// scratch write + per-batch reloads, VGPR_Count=64, 141 us. Fix: 12 individually
// NAMED bf16x8 variables + hand-unrolled PROJ bodies. Named scalars cannot be
// scratch-allocated. launch_bounds(256,2) = the config that allocated 88 regs
// cleanly in round 0. LDS = 40960 B caps at 4 blocks/CU; VGPR ~120 agrees.
__global__ __launch_bounds__(256, 2)
void attn_kernel(const float* __restrict__ x,
                 const unsigned short* __restrict__ wz,
                 float* __restrict__ out) {
  __shared__ unsigned short xs [64 * 128];  // x tile bf16 [t][c], 16B-chunk XOR swizzled
  __shared__ unsigned short qs [64 * 64];   // q rows [t][h]; reused for P
  __shared__ unsigned short ks_[64 * 64];   // k rows [t][h]
  __shared__ unsigned short vts[64 * 64];   // v transposed [h][t]

  const int tid  = threadIdx.x;
  const int wave = tid >> 6;
  const int lane = tid & 63;
  const int quad = lane >> 4;
  const int l15  = lane & 15;
  const int l7   = l15 & 7;
  const int mbase = wave * 16;
  const float scale = 0.08838834764831845f;  // 128^-0.5 (embed dim, per reference)

  // ---- one-time: this wave's 12 weight B-fragments -> 12 NAMED registers (48 VGPRs)
  const unsigned short* wb = wz + (size_t)lane * 8;
#define WLOAD(P, K) (*(const bf16x8*)(wb + ((size_t)((wave * 3 + (P)) * 4 + (K)) << 9)))
  bf16x8 w00 = WLOAD(0, 0), w01 = WLOAD(0, 1), w02 = WLOAD(0, 2), w03 = WLOAD(0, 3);
  bf16x8 w10 = WLOAD(1, 0), w11 = WLOAD(1, 1), w12 = WLOAD(1, 2), w13 = WLOAD(1, 3);
  bf16x8 w20 = WLOAD(2, 0), w21 = WLOAD(2, 1), w22 = WLOAD(2, 2), w23 = WLOAD(2, 3);
#undef WLOAD

  const int b0 = blockIdx.x * BPB;

  for (int bi = 0; bi < BPB; ++bi) {
    const int b = b0 + bi;
    if (bi > 0) __syncthreads();   // all waves done reading previous batch's LDS

    // ---- stage x tile to LDS as bf16 (4 x 16B chunks per thread, coalesced reads)
    #pragma unroll
    for (int k = 0; k < 4; ++k) {
      const int i = tid + 256 * k;          // chunk id: row*16 + c
      const int row = i >> 4, c = i & 15;
      const float* src = x + ((size_t)b * TT + row) * CC + c * 8;
      const f32x4 lo = *(const f32x4*)src;
      const f32x4 hi = *(const f32x4*)(src + 4);
      bf16x8 v;
      #pragma unroll
      for (int j = 0; j < 4; ++j) { v[j] = (__bf16)lo[j]; v[j + 4] = (__bf16)hi[j]; }
      *(bf16x8*)&xs[row * 128 + ((c ^ (row & 7)) << 3)] = v;
    }
    __syncthreads();   // xs ready

    // ---- Phase 1: for each row-tile, this wave's 3 (mat,nt) projection tiles
    #pragma unroll
    for (int mt = 0; mt < 4; ++mt) {
#define XLOAD(K) (*(const bf16x8*)&xs[(mt * 16 + l15) * 128 + (((((K) << 2) + quad) ^ l7) << 3)])
      const bf16x8 xf0 = XLOAD(0), xf1 = XLOAD(1), xf2 = XLOAD(2), xf3 = XLOAD(3);
#undef XLOAD
      // C/D of each MFMA: col = nt*16 + l15, row = mt*16 + quad*4 + r
#define PROJ(P) do {                                                         \
      f32x4 acc_ = {0.f, 0.f, 0.f, 0.f};                                     \
      acc_ = MFMA16(xf0, w##P##0, acc_);                                     \
      acc_ = MFMA16(xf1, w##P##1, acc_);                                     \
      acc_ = MFMA16(xf2, w##P##2, acc_);                                     \
      acc_ = MFMA16(xf3, w##P##3, acc_);                                     \
      const int pi_ = wave * 3 + (P);                                        \
      const int mat_ = pi_ >> 2, nt_ = pi_ & 3;                              \
      if (mat_ == 2) {                                                       \
        /* v stored transposed: 4 consecutive t -> one 8B packed write */    \
        const int h_  = (nt_ << 4) + l15;                                    \
        const int t0_ = (mt << 4) + (quad << 2);                             \
        us4 pk_;                                                             \
        pk_[0] = bfbits(acc_[0]); pk_[1] = bfbits(acc_[1]);                  \
        pk_[2] = bfbits(acc_[2]); pk_[3] = bfbits(acc_[3]);                  \
        *(us4*)&vts[(h_ << 6) + (((t0_ >> 3) ^ (h_ & 7)) << 3) + (t0_ & 7)] = pk_; \
      } else {                                                               \
        unsigned short* dst_ = (mat_ == 0) ? qs : ks_;                       \
        const int col_ = (nt_ << 4) + l15;                                   \
        const int ch_ = col_ >> 3, cj_ = col_ & 7;                           \
        _Pragma("unroll")                                                    \
        for (int r_ = 0; r_ < 4; ++r_) {                                     \
          const int row_ = (mt << 4) + (quad << 2) + r_;                     \
          dst_[(row_ << 6) + ((ch_ ^ (row_ & 7)) << 3) + cj_] = bfbits(acc_[r_]); \
        }                                                                    \
      }                                                                      \
    } while (0)
      PROJ(0); PROJ(1); PROJ(2);
#undef PROJ
    }
    __syncthreads();   // q, k, vT ready (cross-wave)

    // ---- Phase 2: S = q k^T * scale, causal mask, softmax -> P into qs (wave-private rows)
    const bf16x8 aq0 = *(const bf16x8*)&qs[((mbase + l15) << 6) + ((quad ^ l7) << 3)];
    const bf16x8 aq1 = *(const bf16x8*)&qs[((mbase + l15) << 6) + (((4 + quad) ^ l7) << 3)];
    f32x4 sc0 = {0.f, 0.f, 0.f, 0.f}, sc1 = sc0, sc2 = sc0, sc3 = sc0;
#define QK(NT, SC) do {                                                                          \
      const bf16x8 bk0_ = *(const bf16x8*)&ks_[((((NT) << 4) + l15) << 6) + ((quad ^ l7) << 3)]; \
      const bf16x8 bk1_ = *(const bf16x8*)&ks_[((((NT) << 4) + l15) << 6) + (((4 + quad) ^ l7) << 3)]; \
      SC = MFMA16(aq0, bk0_, SC);                                                                \
      SC = MFMA16(aq1, bk1_, SC);                                                                \
    } while (0)
    QK(0, sc0); QK(1, sc1); QK(2, sc2); QK(3, sc3);
#undef QK
    #pragma unroll
    for (int r = 0; r < 4; ++r) {
      const int row = mbase + (quad << 2) + r;
      float v0 = (l15      <= row) ? sc0[r] * scale : -__builtin_inff();
      float v1 = (l15 + 16 <= row) ? sc1[r] * scale : -__builtin_inff();
      float v2 = (l15 + 32 <= row) ? sc2[r] * scale : -__builtin_inff();
      float v3 = (l15 + 48 <= row) ? sc3[r] * scale : -__builtin_inff();
      float m = fmaxf(fmaxf(v0, v1), fmaxf(v2, v3));
      #pragma unroll
      for (int d = 1; d < 16; d <<= 1) m = fmaxf(m, __shfl_xor(m, d, 64));
      v0 = __expf(v0 - m); v1 = __expf(v1 - m); v2 = __expf(v2 - m); v3 = __expf(v3 - m);
      float s = (v0 + v1) + (v2 + v3);
      #pragma unroll
      for (int d = 1; d < 16; d <<= 1) s += __shfl_xor(s, d, 64);
      const float inv = 1.f / s;
      const int rs = row & 7;
      // P overwrites this wave's own q rows; rows are wave-private -> no barrier
      qs[(row << 6) + (((l15 >> 3)     ^ rs) << 3) + (l15 & 7)] = bfbits(v0 * inv);
      qs[(row << 6) + ((((l15 >> 3) + 2) ^ rs) << 3) + (l15 & 7)] = bfbits(v1 * inv);
      qs[(row << 6) + ((((l15 >> 3) + 4) ^ rs) << 3) + (l15 & 7)] = bfbits(v2 * inv);
      qs[(row << 6) + ((((l15 >> 3) + 6) ^ rs) << 3) + (l15 & 7)] = bfbits(v3 * inv);
    }

    // ---- Phase 3: O = P @ V
    const bf16x8 ap0 = *(const bf16x8*)&qs[((mbase + l15) << 6) + ((quad ^ l7) << 3)];
    const bf16x8 ap1 = *(const bf16x8*)&qs[((mbase + l15) << 6) + (((4 + quad) ^ l7) << 3)];
    float* ob = out + (size_t)b * TT * HH;
#define PV(NT) do {                                                                              \
      const bf16x8 bv0_ = *(const bf16x8*)&vts[((((NT) << 4) + l15) << 6) + ((quad ^ l7) << 3)]; \
      const bf16x8 bv1_ = *(const bf16x8*)&vts[((((NT) << 4) + l15) << 6) + (((4 + quad) ^ l7) << 3)]; \
      f32x4 acc_ = {0.f, 0.f, 0.f, 0.f};                                                         \
      acc_ = MFMA16(ap0, bv0_, acc_);                                                            \
      acc_ = MFMA16(ap1, bv1_, acc_);                                                            \
      _Pragma("unroll")                                                                          \
      for (int r_ = 0; r_ < 4; ++r_)                                                             \
        ob[(mbase + (quad << 2) + r_) * HH + ((NT) << 4) + l15] = acc_[r_];                      \
    } while (0)
    PV(0); PV(1); PV(2); PV(3);
#undef PV
  }
}

extern "C" void kernel_launch(void* const* d_in, const int* in_sizes, int n_in,
                              void* d_out, int out_size, void* d_ws, size_t ws_size,
                              hipStream_t stream) {
  const float* x  = (const float*)d_in[0];
  const float* Wq = (const float*)d_in[1];
  const float* Wk = (const float*)d_in[2];
  const float* Wv = (const float*)d_in[3];
  unsigned short* wz = (unsigned short*)d_ws;   // 3*16*64*8 bf16 = 48 KiB scratch
  float* outp = (float*)d_out;

  swizzle_w_kernel<<<(3 * 16 * 64 + 255) / 256, 256, 0, stream>>>(Wq, Wk, Wv, wz);
  attn_kernel<<<NB / BPB, 256, 0, stream>>>(x, wz, outp);
}